// Round 18
// baseline (379.889 us; speedup 1.0000x reference)
//
#include <hip/hip_runtime.h>
#include <hip/hip_bf16.h>
#include <stdint.h>

#define B_   4
#define L_   2048
#define D_   1024
#define H_   16
#define DH_  64
#define DFF_ 4096
#define EPS_ 1e-5f

typedef short s16x8 __attribute__((ext_vector_type(8)));
typedef short s16x4 __attribute__((ext_vector_type(4)));
typedef float f32x4 __attribute__((ext_vector_type(4)));

static __device__ __forceinline__ short f2bf(float f) {
    return __builtin_bit_cast(short, __float2bfloat16(f));
}

static __device__ __forceinline__ void gload_lds16(const void* g, void* l) {
    __builtin_amdgcn_global_load_lds(
        (const __attribute__((address_space(1))) uint32_t*)g,
        (__attribute__((address_space(3))) uint32_t*)l, 16, 0, 0);
}

// ---------------- transpose + f32 -> bf16 convert (weights, once) -------------
__global__ __launch_bounds__(256) void transpose_kernel(
    const float* __restrict__ in, short* __restrict__ out, int R, int C)
{
    __shared__ float tile[32][33];
    const int bx = blockIdx.x * 32, by = blockIdx.y * 32;
    const int tx = threadIdx.x & 31, ty = threadIdx.x >> 5;  // 32 x 8
#pragma unroll
    for (int i = 0; i < 32; i += 8)
        tile[ty + i][tx] = in[(size_t)(by + ty + i) * C + bx + tx];
    __syncthreads();
#pragma unroll
    for (int i = 0; i < 32; i += 8)
        out[(size_t)(bx + ty + i) * R + by + tx] = f2bf(tile[tx][ty + i]);
}

// ---------------- concat 3 bias vectors (1024 each) -----------------------------
__global__ __launch_bounds__(256) void concat3_kernel(
    const float* __restrict__ a, const float* __restrict__ b,
    const float* __restrict__ c, float* __restrict__ o)
{
    const int i = blockIdx.x * 256 + threadIdx.x;   // 0..3071
    o[i] = (i < 1024) ? a[i] : (i < 2048 ? b[i - 1024] : c[i - 2048]);
}

// ---------------- V transpose: [B*L][D] bf16 -> [(b*H+h)*DH+d][L] bf16 ---------
__global__ __launch_bounds__(256) void vtrans_kernel(
    const short* __restrict__ V, short* __restrict__ Vt)
{
    __shared__ short t[64][72];
    const int l0 = blockIdx.x * 64;
    const int bh = blockIdx.y;          // b*H + h
    const int b = bh >> 4, h = bh & 15;
    const int tid = threadIdx.x;
    const int rr = tid >> 3, cc = tid & 7;
#pragma unroll
    for (int i = 0; i < 2; ++i) {
        const int row = i * 32 + rr;
        *(s16x8*)&t[row][cc * 8] =
            *(const s16x8*)(V + (size_t)(b * L_ + l0 + row) * D_ + h * DH_ + cc * 8);
    }
    __syncthreads();
#pragma unroll
    for (int i = 0; i < 2; ++i) {
        const int d = i * 32 + rr;
        const int lp0 = cc * 8;
        s16x8 o;
#pragma unroll
        for (int j = 0; j < 8; ++j) o[j] = t[lp0 + j][d];
        *(s16x8*)(Vt + ((size_t)bh * DH_ + d) * L_ + l0 + lp0) = o;
    }
}

// ---------------- layernorm: f32 in -> bf16 out --------------------------------
__global__ __launch_bounds__(256) void ln_kernel(
    const float* __restrict__ x, const float* __restrict__ g,
    const float* __restrict__ bta, short* __restrict__ out)
{
    __shared__ float sm[8];
    const int row = blockIdx.x;
    const int t = threadIdx.x;
    const float4 v = ((const float4*)(x + (size_t)row * D_))[t];
    float s1 = v.x + v.y + v.z + v.w;
    float s2 = v.x * v.x + v.y * v.y + v.z * v.z + v.w * v.w;
#pragma unroll
    for (int off = 1; off < 64; off <<= 1) {
        s1 += __shfl_xor(s1, off);
        s2 += __shfl_xor(s2, off);
    }
    if ((t & 63) == 0) { sm[t >> 6] = s1; sm[4 + (t >> 6)] = s2; }
    __syncthreads();
    s1 = sm[0] + sm[1] + sm[2] + sm[3];
    s2 = sm[4] + sm[5] + sm[6] + sm[7];
    const float mu  = s1 * (1.f / D_);
    const float var = s2 * (1.f / D_) - mu * mu;
    const float rs  = rsqrtf(var + EPS_);
    const float4 gv = ((const float4*)g)[t];
    const float4 bv = ((const float4*)bta)[t];
    s16x4 o;
    o[0] = f2bf((v.x - mu) * rs * gv.x + bv.x);
    o[1] = f2bf((v.y - mu) * rs * gv.y + bv.y);
    o[2] = f2bf((v.z - mu) * rs * gv.z + bv.z);
    o[3] = f2bf((v.w - mu) * rs * gv.w + bv.w);
    *(s16x4*)(out + (size_t)row * D_ + t * 4) = o;
}

// ---------------- GEMM: C[M,N] = A[M,K](bf16) @ Bt[N,K]^T (bf16) + epilogue ----
// R16-proven: 128M x 256N tile, BK=64, 512 threads (8 waves 2x4), 3-ring LDS,
// one barrier per 32 MFMA, counted vmcnt(6), T1 chunked XCD swizzle.
// chunk' = chunk ^ (row&7), both sides.
// MODE 1: bf16=relu(acc+bias); 2: f32=acc+bias+res; 3: bf16 QKV-split.
template <int MODE>
__global__ __launch_bounds__(512) void gemm_kernel(
    const short* __restrict__ A, const short* __restrict__ Bt,
    const float* __restrict__ bias, const float* __restrict__ res,
    void* __restrict__ out, int M, int N, int K)
{
    __shared__ short As[3][128 * 64];   // 48 KB
    __shared__ short Bs[3][256 * 64];   // 96 KB

    // ---- T1 chunked XCD swizzle (bijective; nwg % 8 == 0) ----
    const int nx = gridDim.x;
    const int flat = blockIdx.y * nx + blockIdx.x;
    const int nper = (nx * gridDim.y) >> 3;
    const int nid = (flat & 7) * nper + (flat >> 3);
    const int m0 = (nid / nx) * 128;
    const int n0 = (nid % nx) * 256;

    const int tid = threadIdx.x;
    const int w = tid >> 6, l = tid & 63;
    const int wm = w >> 2, wn = w & 3;
    const int lg = l >> 4, li = l & 15;

    // A staging: 2 issues/thread; B staging: 4 issues/thread (chunk pre-swizzled)
    const short* aSrc[2];
    int adst[2];
#pragma unroll
    for (int i = 0; i < 2; ++i) {
        const int s = i * 512 + tid;          // 0..1023
        const int row = s >> 3;               // 0..127
        const int ch = (s & 7) ^ (row & 7);
        aSrc[i] = A + (size_t)(m0 + row) * K + ch * 8;
        adst[i] = s * 8;
    }
    const short* bSrc[4];
    int bdst[4];
#pragma unroll
    for (int i = 0; i < 4; ++i) {
        const int s = i * 512 + tid;          // 0..2047
        const int row = s >> 3;               // 0..255
        const int ch = (s & 7) ^ (row & 7);
        bSrc[i] = Bt + (size_t)(n0 + row) * K + ch * 8;
        bdst[i] = s * 8;
    }

    // fragment read offsets (swizzled): desired chunk c = ks*4+lg -> pos c^(row&7)
    int aoff[4][2], boff[4][2];
#pragma unroll
    for (int m = 0; m < 4; ++m)
#pragma unroll
        for (int ks = 0; ks < 2; ++ks) {
            const int rowA = wm * 64 + m * 16 + li;
            aoff[m][ks] = rowA * 64 + (((ks * 4 + lg) ^ (rowA & 7)) * 8);
        }
#pragma unroll
    for (int n = 0; n < 4; ++n)
#pragma unroll
        for (int ks = 0; ks < 2; ++ks) {
            const int rowB = wn * 64 + n * 16 + li;
            boff[n][ks] = rowB * 64 + (((ks * 4 + lg) ^ (rowB & 7)) * 8);
        }

    f32x4 acc[4][4] = {};
    const int nT = K >> 6;

    // prologue: stage tile 0 into ring slot 0 (6 loads/thread)
#pragma unroll
    for (int i = 0; i < 2; ++i) gload_lds16(aSrc[i], &As[0][adst[i]]);
#pragma unroll
    for (int i = 0; i < 4; ++i) gload_lds16(bSrc[i], &Bs[0][bdst[i]]);

    int cur = 0, nxt = 1;
    for (int t = 0; t < nT; ++t) {
        if (t + 1 < nT) {
            const int k1 = (t + 1) << 6;
#pragma unroll
            for (int i = 0; i < 2; ++i) gload_lds16(aSrc[i] + k1, &As[nxt][adst[i]]);
#pragma unroll
            for (int i = 0; i < 4; ++i) gload_lds16(bSrc[i] + k1, &Bs[nxt][bdst[i]]);
            asm volatile("s_waitcnt vmcnt(6)" ::: "memory");
        } else {
            asm volatile("s_waitcnt vmcnt(0)" ::: "memory");
        }
        __builtin_amdgcn_s_barrier();
        __builtin_amdgcn_sched_barrier(0);

        const short* as = &As[cur][0];
        const short* bs = &Bs[cur][0];
        s16x8 af[4][2], bf[4][2];
#pragma unroll
        for (int m = 0; m < 4; ++m)
#pragma unroll
            for (int ks = 0; ks < 2; ++ks)
                af[m][ks] = *(const s16x8*)&as[aoff[m][ks]];
#pragma unroll
        for (int n = 0; n < 4; ++n)
#pragma unroll
            for (int ks = 0; ks < 2; ++ks)
                bf[n][ks] = *(const s16x8*)&bs[boff[n][ks]];
#pragma unroll
        for (int ks = 0; ks < 2; ++ks)
#pragma unroll
            for (int m = 0; m < 4; ++m)
#pragma unroll
                for (int n = 0; n < 4; ++n)
                    acc[m][n] = __builtin_amdgcn_mfma_f32_16x16x32_bf16(
                        af[m][ks], bf[n][ks], acc[m][n], 0, 0, 0);

        cur = nxt;
        nxt = (nxt == 2) ? 0 : nxt + 1;
    }

#pragma unroll
    for (int m = 0; m < 4; ++m) {
#pragma unroll
        for (int n = 0; n < 4; ++n) {
            const int col = n0 + wn * 64 + n * 16 + li;
            const float bv = bias[col];
#pragma unroll
            for (int r = 0; r < 4; ++r) {
                const int row = m0 + wm * 64 + m * 16 + lg * 4 + r;
                float v = acc[m][n][r] + bv;
                if (MODE == 1) v = v > 0.f ? v : 0.f;
                if (MODE == 2) {
                    float* o = (float*)out;
                    o[(size_t)row * N + col] = v + res[(size_t)row * N + col];
                } else if (MODE == 3) {
                    short* o = (short*)out;
                    o[(size_t)(col >> 10) * (8192ull * 1024) +
                      (size_t)row * 1024 + (col & 1023)] = f2bf(v);
                } else {
                    short* o = (short*)out;
                    o[(size_t)row * N + col] = f2bf(v);
                }
            }
        }
    }
}

// ---------------- flash attention (causal): KVBLK=128, 3-ring, counted vmcnt ---
// grid (16, H, B); 512 threads; wave w owns 16 q-rows; KV tiles of 128
// (barrier amortization: one vmcnt+barrier per 32 MFMA, the R16-GEMM ratio).
// K tile [128][64] swizzled chunk^(row&7); V^T tile [64][128] swizzled
// chunk^(row&15); P [16][136] per wave. exp2 softmax, defer-max 11.5.
__global__ __launch_bounds__(512) void attn_kernel(
    const short* __restrict__ Q, const short* __restrict__ K,
    const short* __restrict__ Vt, short* __restrict__ O)
{
    __shared__ short Kbuf[3][128 * 64];   // 48 KB
    __shared__ short Vbuf[3][64 * 128];   // 48 KB
    __shared__ short Ps[8][16 * 136];     // 34 KB

    const int xx = blockIdx.x;          // 0..15
    const int h = blockIdx.y, b = blockIdx.z;
    const int pr = xx >> 1;
    const int u = (pr + b * 2) & 7;
    const int qblk = ((xx + b) & 1) ? (15 - u) : u;   // balanced causal work
    const int tid = threadIdx.x;
    const int w = tid >> 6, l = tid & 63;
    const int lg = l >> 4, li = l & 15;
    const size_t headQ = ((size_t)b * L_) * D_ + (size_t)h * DH_;
    const size_t headV = ((size_t)(b * H_ + h) * DH_) * L_;
    const int q0 = qblk * 128;
    const int qw = q0 + w * 16;
    const float sc2 = 0.125f * 1.44269504f;   // scale * log2(e)

    s16x8 qf[2];
    {
        const short* qr = Q + headQ + (size_t)(qw + li) * D_;
        qf[0] = *(const s16x8*)(qr + lg * 8);
        qf[1] = *(const s16x8*)(qr + 32 + lg * 8);
    }

    // K staging: 2 issues/thread (128 rows x 8 chunks, chunk pre-swizzled)
    const short* kSrc[2];
    int kdst[2];
#pragma unroll
    for (int i = 0; i < 2; ++i) {
        const int s = i * 512 + tid;          // 0..1023
        const int row = s >> 3;               // kv 0..127
        const int ch = (s & 7) ^ (row & 7);
        kSrc[i] = K + headQ + (size_t)row * D_ + ch * 8;
        kdst[i] = s * 8;
    }
    // V staging: 2 issues/thread (64 rows x 16 chunks, chunk pre-swizzled)
    const short* vSrc[2];
    int vdst[2];
#pragma unroll
    for (int i = 0; i < 2; ++i) {
        const int s = i * 512 + tid;          // 0..1023
        const int row = s >> 4;               // d 0..63
        const int ch = (s & 15) ^ (row & 15);
        vSrc[i] = Vt + headV + (size_t)row * L_ + ch * 8;
        vdst[i] = s * 8;
    }

    // K fragment read offsets: row = blk*16+li, chunk (lg / lg+4) ^ (row&7)
    int koff0[8], koff1[8];
#pragma unroll
    for (int blk = 0; blk < 8; ++blk) {
        const int row = blk * 16 + li;
        const int hh = row & 7;
        koff0[blk] = row * 64 + ((lg ^ hh) * 8);
        koff1[blk] = row * 64 + (((lg + 4) ^ hh) * 8);
    }
    // V fragment read offsets: row = dblk*16+li (row&15 = li), chunk (j*4+lg)^li
    int voff[4][4];
#pragma unroll
    for (int dblk = 0; dblk < 4; ++dblk)
#pragma unroll
        for (int j = 0; j < 4; ++j)
            voff[dblk][j] = (dblk * 16 + li) * 128 + (((j * 4 + lg) ^ li) * 8);

    float m_r = -1e30f, l_r = 0.f;
    f32x4 oacc[4] = {};
    short* pw = &Ps[w][0];

    const int nt = qblk + 1;   // KV tiles of 128 covering kv 0 .. q0+127

    // prologue: stage tile 0 into ring slot 0
#pragma unroll
    for (int i = 0; i < 2; ++i) {
        gload_lds16(kSrc[i], &Kbuf[0][kdst[i]]);
        gload_lds16(vSrc[i], &Vbuf[0][vdst[i]]);
    }

    int cur = 0, nxt = 1;
    for (int t = 0; t < nt; ++t) {
        const int kv0 = t * 128;
        if (t + 1 < nt) {
            const int nkv = kv0 + 128;
#pragma unroll
            for (int i = 0; i < 2; ++i) {
                gload_lds16(kSrc[i] + (size_t)nkv * D_, &Kbuf[nxt][kdst[i]]);
                gload_lds16(vSrc[i] + nkv, &Vbuf[nxt][vdst[i]]);
            }
            asm volatile("s_waitcnt vmcnt(4)" ::: "memory");
        } else {
            asm volatile("s_waitcnt vmcnt(0)" ::: "memory");
        }
        __builtin_amdgcn_s_barrier();
        __builtin_amdgcn_sched_barrier(0);

        const short* kb = &Kbuf[cur][0];
        const short* vb = &Vbuf[cur][0];

        // ---- QK^T swapped: S^T[kv][q] over 128 kv (16 MFMA) ----
        f32x4 s[8];
        __builtin_amdgcn_s_setprio(1);
#pragma unroll
        for (int blk = 0; blk < 8; ++blk) {
            const s16x8 kf0 = *(const s16x8*)&kb[koff0[blk]];
            const s16x8 kf1 = *(const s16x8*)&kb[koff1[blk]];
            f32x4 c = {0.f, 0.f, 0.f, 0.f};
            c = __builtin_amdgcn_mfma_f32_16x16x32_bf16(kf0, qf[0], c, 0, 0, 0);
            c = __builtin_amdgcn_mfma_f32_16x16x32_bf16(kf1, qf[1], c, 0, 0, 0);
            s[blk] = c;
        }
        __builtin_amdgcn_s_setprio(0);

        // ---- causal mask (last tile only; kv0+127 > qw iff t == qblk) ----
        if (kv0 + 127 > qw) {
            const int q = qw + li;
#pragma unroll
            for (int blk = 0; blk < 8; ++blk) {
                const int kvb = kv0 + blk * 16 + lg * 4;
#pragma unroll
                for (int r = 0; r < 4; ++r)
                    if (kvb + r > q) s[blk][r] = -1e30f;
            }
        }

        // ---- online softmax (log2 domain), defer-max ----
        float mb[8];
#pragma unroll
        for (int blk = 0; blk < 8; ++blk)
            mb[blk] = fmaxf(fmaxf(s[blk][0], s[blk][1]),
                            fmaxf(s[blk][2], s[blk][3]));
        float mm = fmaxf(fmaxf(fmaxf(mb[0], mb[1]), fmaxf(mb[2], mb[3])),
                         fmaxf(fmaxf(mb[4], mb[5]), fmaxf(mb[6], mb[7])));
        mm = fmaxf(mm, __shfl_xor(mm, 16));
        mm = fmaxf(mm, __shfl_xor(mm, 32));
        const float mxs = mm * sc2;

        float p[8][4];
        if (__all(mxs <= m_r + 11.5f)) {
            float ps[8];
#pragma unroll
            for (int blk = 0; blk < 8; ++blk) {
#pragma unroll
                for (int r = 0; r < 4; ++r)
                    p[blk][r] = __builtin_amdgcn_exp2f(
                        fmaf(s[blk][r], sc2, -m_r));
                ps[blk] = (p[blk][0] + p[blk][1]) + (p[blk][2] + p[blk][3]);
            }
            float sum = ((ps[0] + ps[1]) + (ps[2] + ps[3])) +
                        ((ps[4] + ps[5]) + (ps[6] + ps[7]));
            sum += __shfl_xor(sum, 16);
            sum += __shfl_xor(sum, 32);
            l_r += sum;
        } else {
            const float mn = fmaxf(m_r, mxs);
            const float fac = __builtin_amdgcn_exp2f(m_r - mn);
            m_r = mn;
            float ps[8];
#pragma unroll
            for (int blk = 0; blk < 8; ++blk) {
#pragma unroll
                for (int r = 0; r < 4; ++r)
                    p[blk][r] = __builtin_amdgcn_exp2f(
                        fmaf(s[blk][r], sc2, -mn));
                ps[blk] = (p[blk][0] + p[blk][1]) + (p[blk][2] + p[blk][3]);
            }
            float sum = ((ps[0] + ps[1]) + (ps[2] + ps[3])) +
                        ((ps[4] + ps[5]) + (ps[6] + ps[7]));
            sum += __shfl_xor(sum, 16);
            sum += __shfl_xor(sum, 32);
            l_r = l_r * fac + sum;
#pragma unroll
            for (int d = 0; d < 4; ++d)
#pragma unroll
                for (int r = 0; r < 4; ++r)
                    oacc[d][r] *= fac;
        }

        // ---- P -> LDS: P[q=li][kv = blk*16 + lg*4 + r] ----
#pragma unroll
        for (int blk = 0; blk < 8; ++blk) {
            s16x4 pk;
#pragma unroll
            for (int r = 0; r < 4; ++r) pk[r] = f2bf(p[blk][r]);
            *(s16x4*)&pw[li * 136 + blk * 16 + lg * 4] = pk;
        }
        asm volatile("s_waitcnt lgkmcnt(0)" ::: "memory");
        __builtin_amdgcn_sched_barrier(0);
        s16x8 pa[4];
#pragma unroll
        for (int j = 0; j < 4; ++j)
            pa[j] = *(const s16x8*)&pw[li * 136 + j * 32 + lg * 8];

        // ---- PV: O^T[d][q] += V^T @ P^T over 128 kv (16 MFMA) ----
        __builtin_amdgcn_s_setprio(1);
#pragma unroll
        for (int dblk = 0; dblk < 4; ++dblk)
#pragma unroll
            for (int j = 0; j < 4; ++j) {
                const s16x8 vf = *(const s16x8*)&vb[voff[dblk][j]];
                oacc[dblk] = __builtin_amdgcn_mfma_f32_16x16x32_bf16(
                    vf, pa[j], oacc[dblk], 0, 0, 0);
            }
        __builtin_amdgcn_s_setprio(0);

        cur = nxt;
        nxt = (nxt == 2) ? 0 : nxt + 1;
    }

    const float inv = 1.f / l_r;
#pragma unroll
    for (int dblk = 0; dblk < 4; ++dblk) {
        s16x4 ov;
#pragma unroll
        for (int r = 0; r < 4; ++r) ov[r] = f2bf(oacc[dblk][r] * inv);
        *(s16x4*)(O + headQ + (size_t)(qw + li) * D_ + dblk * 16 + lg * 4) = ov;
    }
}

// ---------------- launch --------------------------------------------------------
extern "C" void kernel_launch(void* const* d_in, const int* in_sizes, int n_in,
                              void* d_out, int out_size, void* d_ws, size_t ws_size,
                              hipStream_t stream)
{
    const float* X   = (const float*)d_in[0];
    const float* WQ  = (const float*)d_in[1];
    const float* bQ  = (const float*)d_in[2];
    const float* WK  = (const float*)d_in[3];
    const float* bK  = (const float*)d_in[4];
    const float* WV  = (const float*)d_in[5];
    const float* bV  = (const float*)d_in[6];
    const float* WO  = (const float*)d_in[7];
    const float* bO  = (const float*)d_in[8];
    const float* W1  = (const float*)d_in[9];
    const float* b1  = (const float*)d_in[10];
    const float* W2  = (const float*)d_in[11];
    const float* b2  = (const float*)d_in[12];
    const float* g1  = (const float*)d_in[13];
    const float* be1 = (const float*)d_in[14];
    const float* g2  = (const float*)d_in[15];
    const float* be2 = (const float*)d_in[16];
    float* out = (float*)d_out;

    char* ws = (char*)d_ws;
    const size_t MB = 1u << 20;
    short* WQKVt = (short*)(ws + 0 * MB);  // [3072][1024] (WQt|WKt|WVt contiguous)
    short* WOt = (short*)(ws + 6 * MB);
    short* W1t = (short*)(ws + 8 * MB);    // [4096][1024]
    short* W2t = (short*)(ws + 16 * MB);   // [1024][4096]
    short* Xn  = (short*)(ws + 24 * MB);   // [8192][1024] (LN1, reused for LN2)
    short* Qb  = (short*)(ws + 40 * MB);   // [8192][1024]; Kb=+16MB, Vb=+32MB
    short* Vb  = (short*)(ws + 72 * MB);
    short* Vtb = (short*)(ws + 88 * MB);   // [64*64][2048] V^T
    float* bQKV = (float*)(ws + 88 * MB);  // 3072 f32, dead before vtrans writes Vtb
    short* AV  = (short*)(ws + 72 * MB);   // reuses Vb after vtrans
    short* H1  = (short*)(ws + 40 * MB);   // [8192][4096], reuses Q/K/V (dead)

    const dim3 tb(256);

    transpose_kernel<<<dim3(32, 32), tb, 0, stream>>>(WQ, WQKVt, 1024, 1024);
    transpose_kernel<<<dim3(32, 32), tb, 0, stream>>>(WK, WQKVt + 1024 * 1024, 1024, 1024);
    transpose_kernel<<<dim3(32, 32), tb, 0, stream>>>(WV, WQKVt + 2 * 1024 * 1024, 1024, 1024);
    transpose_kernel<<<dim3(32, 32), tb, 0, stream>>>(WO, WOt, 1024, 1024);
    transpose_kernel<<<dim3(128, 32), tb, 0, stream>>>(W1, W1t, 1024, 4096);
    transpose_kernel<<<dim3(32, 128), tb, 0, stream>>>(W2, W2t, 4096, 1024);
    concat3_kernel<<<dim3(12), tb, 0, stream>>>(bQ, bK, bV, bQKV);

    ln_kernel<<<8192, tb, 0, stream>>>(X, g1, be1, Xn);

    // fused QKV GEMM: N=3072, split outputs to Qb/Kb/Vb
    gemm_kernel<3><<<dim3(12, 64), dim3(512), 0, stream>>>(
        Xn, WQKVt, bQKV, nullptr, Qb, 8192, 3072, 1024);

    vtrans_kernel<<<dim3(L_ / 64, B_ * H_), tb, 0, stream>>>(Vb, Vtb);

    attn_kernel<<<dim3(L_ / 128, H_, B_), dim3(512), 0, stream>>>(
        Qb, Qb + 8192ull * 1024, Vtb, AV);

    gemm_kernel<2><<<dim3(4, 64), dim3(512), 0, stream>>>(
        AV, WOt, bO, X, out, 8192, 1024, 1024);

    ln_kernel<<<8192, tb, 0, stream>>>(out, g2, be2, Xn);

    gemm_kernel<1><<<dim3(16, 64), dim3(512), 0, stream>>>(
        Xn, W1t, b1, nullptr, H1, 8192, 4096, 1024);
    gemm_kernel<2><<<dim3(4, 64), dim3(512), 0, stream>>>(
        H1, W2t, b2, out, out, 8192, 1024, 4096);
}

// Round 19
// 368.159 us; speedup vs baseline: 1.0319x; 1.0319x over previous
//
#include <hip/hip_runtime.h>
#include <hip/hip_bf16.h>
#include <stdint.h>

#define B_   4
#define L_   2048
#define D_   1024
#define H_   16
#define DH_  64
#define DFF_ 4096
#define EPS_ 1e-5f

typedef short s16x8 __attribute__((ext_vector_type(8)));
typedef short s16x4 __attribute__((ext_vector_type(4)));
typedef float f32x4 __attribute__((ext_vector_type(4)));

static __device__ __forceinline__ short f2bf(float f) {
    return __builtin_bit_cast(short, __float2bfloat16(f));
}

static __device__ __forceinline__ void gload_lds16(const void* g, void* l) {
    __builtin_amdgcn_global_load_lds(
        (const __attribute__((address_space(1))) uint32_t*)g,
        (__attribute__((address_space(3))) uint32_t*)l, 16, 0, 0);
}

// ---------------- transpose + f32 -> bf16 convert (weights, once) -------------
// z-fused variant: blockIdx.z selects among up to 4 equally-shaped matrices.
__global__ __launch_bounds__(256) void transpose4_kernel(
    const float* __restrict__ in0, const float* __restrict__ in1,
    const float* __restrict__ in2, const float* __restrict__ in3,
    short* __restrict__ out0, short* __restrict__ out1,
    short* __restrict__ out2, short* __restrict__ out3, int R, int C)
{
    const float* ins[4] = {in0, in1, in2, in3};
    short* outs[4] = {out0, out1, out2, out3};
    const float* in = ins[blockIdx.z];
    short* out = outs[blockIdx.z];
    __shared__ float tile[32][33];
    const int bx = blockIdx.x * 32, by = blockIdx.y * 32;
    const int tx = threadIdx.x & 31, ty = threadIdx.x >> 5;  // 32 x 8
#pragma unroll
    for (int i = 0; i < 32; i += 8)
        tile[ty + i][tx] = in[(size_t)(by + ty + i) * C + bx + tx];
    __syncthreads();
#pragma unroll
    for (int i = 0; i < 32; i += 8)
        out[(size_t)(bx + ty + i) * R + by + tx] = f2bf(tile[tx][ty + i]);
}

__global__ __launch_bounds__(256) void transpose_kernel(
    const float* __restrict__ in, short* __restrict__ out, int R, int C)
{
    __shared__ float tile[32][33];
    const int bx = blockIdx.x * 32, by = blockIdx.y * 32;
    const int tx = threadIdx.x & 31, ty = threadIdx.x >> 5;  // 32 x 8
#pragma unroll
    for (int i = 0; i < 32; i += 8)
        tile[ty + i][tx] = in[(size_t)(by + ty + i) * C + bx + tx];
    __syncthreads();
#pragma unroll
    for (int i = 0; i < 32; i += 8)
        out[(size_t)(bx + ty + i) * R + by + tx] = f2bf(tile[tx][ty + i]);
}

// ---------------- concat 3 bias vectors (1024 each) -----------------------------
__global__ __launch_bounds__(256) void concat3_kernel(
    const float* __restrict__ a, const float* __restrict__ b,
    const float* __restrict__ c, float* __restrict__ o)
{
    const int i = blockIdx.x * 256 + threadIdx.x;   // 0..3071
    o[i] = (i < 1024) ? a[i] : (i < 2048 ? b[i - 1024] : c[i - 2048]);
}

// ---------------- V transpose: [B*L][D] bf16 -> [(b*H+h)*DH+d][L] bf16 ---------
__global__ __launch_bounds__(256) void vtrans_kernel(
    const short* __restrict__ V, short* __restrict__ Vt)
{
    __shared__ short t[64][72];
    const int l0 = blockIdx.x * 64;
    const int bh = blockIdx.y;          // b*H + h
    const int b = bh >> 4, h = bh & 15;
    const int tid = threadIdx.x;
    const int rr = tid >> 3, cc = tid & 7;
#pragma unroll
    for (int i = 0; i < 2; ++i) {
        const int row = i * 32 + rr;
        *(s16x8*)&t[row][cc * 8] =
            *(const s16x8*)(V + (size_t)(b * L_ + l0 + row) * D_ + h * DH_ + cc * 8);
    }
    __syncthreads();
#pragma unroll
    for (int i = 0; i < 2; ++i) {
        const int d = i * 32 + rr;
        const int lp0 = cc * 8;
        s16x8 o;
#pragma unroll
        for (int j = 0; j < 8; ++j) o[j] = t[lp0 + j][d];
        *(s16x8*)(Vt + ((size_t)bh * DH_ + d) * L_ + l0 + lp0) = o;
    }
}

// ---------------- layernorm: f32 in -> bf16 out --------------------------------
__global__ __launch_bounds__(256) void ln_kernel(
    const float* __restrict__ x, const float* __restrict__ g,
    const float* __restrict__ bta, short* __restrict__ out)
{
    __shared__ float sm[8];
    const int row = blockIdx.x;
    const int t = threadIdx.x;
    const float4 v = ((const float4*)(x + (size_t)row * D_))[t];
    float s1 = v.x + v.y + v.z + v.w;
    float s2 = v.x * v.x + v.y * v.y + v.z * v.z + v.w * v.w;
#pragma unroll
    for (int off = 1; off < 64; off <<= 1) {
        s1 += __shfl_xor(s1, off);
        s2 += __shfl_xor(s2, off);
    }
    if ((t & 63) == 0) { sm[t >> 6] = s1; sm[4 + (t >> 6)] = s2; }
    __syncthreads();
    s1 = sm[0] + sm[1] + sm[2] + sm[3];
    s2 = sm[4] + sm[5] + sm[6] + sm[7];
    const float mu  = s1 * (1.f / D_);
    const float var = s2 * (1.f / D_) - mu * mu;
    const float rs  = rsqrtf(var + EPS_);
    const float4 gv = ((const float4*)g)[t];
    const float4 bv = ((const float4*)bta)[t];
    s16x4 o;
    o[0] = f2bf((v.x - mu) * rs * gv.x + bv.x);
    o[1] = f2bf((v.y - mu) * rs * gv.y + bv.y);
    o[2] = f2bf((v.z - mu) * rs * gv.z + bv.z);
    o[3] = f2bf((v.w - mu) * rs * gv.w + bv.w);
    *(s16x4*)(out + (size_t)row * D_ + t * 4) = o;
}

// ---------------- GEMM: C[M,N] = A[M,K](bf16) @ Bt[N,K]^T (bf16) + epilogue ----
// R16-proven: 128M x 256N tile, BK=64, 512 threads (8 waves 2x4), 3-ring LDS,
// one barrier per 32 MFMA, counted vmcnt(6), T1 chunked XCD swizzle.
// chunk' = chunk ^ (row&7), both sides.
// MODE 1: bf16=relu(acc+bias); 2: f32=acc+bias+res; 3: bf16 QKV-split.
template <int MODE>
__global__ __launch_bounds__(512) void gemm_kernel(
    const short* __restrict__ A, const short* __restrict__ Bt,
    const float* __restrict__ bias, const float* __restrict__ res,
    void* __restrict__ out, int M, int N, int K)
{
    __shared__ short As[3][128 * 64];   // 48 KB
    __shared__ short Bs[3][256 * 64];   // 96 KB

    // ---- T1 chunked XCD swizzle (bijective; nwg % 8 == 0) ----
    const int nx = gridDim.x;
    const int flat = blockIdx.y * nx + blockIdx.x;
    const int nper = (nx * gridDim.y) >> 3;
    const int nid = (flat & 7) * nper + (flat >> 3);
    const int m0 = (nid / nx) * 128;
    const int n0 = (nid % nx) * 256;

    const int tid = threadIdx.x;
    const int w = tid >> 6, l = tid & 63;
    const int wm = w >> 2, wn = w & 3;
    const int lg = l >> 4, li = l & 15;

    // A staging: 2 issues/thread; B staging: 4 issues/thread (chunk pre-swizzled)
    const short* aSrc[2];
    int adst[2];
#pragma unroll
    for (int i = 0; i < 2; ++i) {
        const int s = i * 512 + tid;          // 0..1023
        const int row = s >> 3;               // 0..127
        const int ch = (s & 7) ^ (row & 7);
        aSrc[i] = A + (size_t)(m0 + row) * K + ch * 8;
        adst[i] = s * 8;
    }
    const short* bSrc[4];
    int bdst[4];
#pragma unroll
    for (int i = 0; i < 4; ++i) {
        const int s = i * 512 + tid;          // 0..2047
        const int row = s >> 3;               // 0..255
        const int ch = (s & 7) ^ (row & 7);
        bSrc[i] = Bt + (size_t)(n0 + row) * K + ch * 8;
        bdst[i] = s * 8;
    }

    // fragment read offsets (swizzled): desired chunk c = ks*4+lg -> pos c^(row&7)
    int aoff[4][2], boff[4][2];
#pragma unroll
    for (int m = 0; m < 4; ++m)
#pragma unroll
        for (int ks = 0; ks < 2; ++ks) {
            const int rowA = wm * 64 + m * 16 + li;
            aoff[m][ks] = rowA * 64 + (((ks * 4 + lg) ^ (rowA & 7)) * 8);
        }
#pragma unroll
    for (int n = 0; n < 4; ++n)
#pragma unroll
        for (int ks = 0; ks < 2; ++ks) {
            const int rowB = wn * 64 + n * 16 + li;
            boff[n][ks] = rowB * 64 + (((ks * 4 + lg) ^ (rowB & 7)) * 8);
        }

    f32x4 acc[4][4] = {};
    const int nT = K >> 6;

    // prologue: stage tile 0 into ring slot 0 (6 loads/thread)
#pragma unroll
    for (int i = 0; i < 2; ++i) gload_lds16(aSrc[i], &As[0][adst[i]]);
#pragma unroll
    for (int i = 0; i < 4; ++i) gload_lds16(bSrc[i], &Bs[0][bdst[i]]);

    int cur = 0, nxt = 1;
    for (int t = 0; t < nT; ++t) {
        if (t + 1 < nT) {
            const int k1 = (t + 1) << 6;
#pragma unroll
            for (int i = 0; i < 2; ++i) gload_lds16(aSrc[i] + k1, &As[nxt][adst[i]]);
#pragma unroll
            for (int i = 0; i < 4; ++i) gload_lds16(bSrc[i] + k1, &Bs[nxt][bdst[i]]);
            asm volatile("s_waitcnt vmcnt(6)" ::: "memory");
        } else {
            asm volatile("s_waitcnt vmcnt(0)" ::: "memory");
        }
        __builtin_amdgcn_s_barrier();
        __builtin_amdgcn_sched_barrier(0);

        const short* as = &As[cur][0];
        const short* bs = &Bs[cur][0];
        s16x8 af[4][2], bf[4][2];
#pragma unroll
        for (int m = 0; m < 4; ++m)
#pragma unroll
            for (int ks = 0; ks < 2; ++ks)
                af[m][ks] = *(const s16x8*)&as[aoff[m][ks]];
#pragma unroll
        for (int n = 0; n < 4; ++n)
#pragma unroll
            for (int ks = 0; ks < 2; ++ks)
                bf[n][ks] = *(const s16x8*)&bs[boff[n][ks]];
#pragma unroll
        for (int ks = 0; ks < 2; ++ks)
#pragma unroll
            for (int m = 0; m < 4; ++m)
#pragma unroll
                for (int n = 0; n < 4; ++n)
                    acc[m][n] = __builtin_amdgcn_mfma_f32_16x16x32_bf16(
                        af[m][ks], bf[n][ks], acc[m][n], 0, 0, 0);

        cur = nxt;
        nxt = (nxt == 2) ? 0 : nxt + 1;
    }

#pragma unroll
    for (int m = 0; m < 4; ++m) {
#pragma unroll
        for (int n = 0; n < 4; ++n) {
            const int col = n0 + wn * 64 + n * 16 + li;
            const float bv = bias[col];
#pragma unroll
            for (int r = 0; r < 4; ++r) {
                const int row = m0 + wm * 64 + m * 16 + lg * 4 + r;
                float v = acc[m][n][r] + bv;
                if (MODE == 1) v = v > 0.f ? v : 0.f;
                if (MODE == 2) {
                    float* o = (float*)out;
                    o[(size_t)row * N + col] = v + res[(size_t)row * N + col];
                } else if (MODE == 3) {
                    short* o = (short*)out;
                    o[(size_t)(col >> 10) * (8192ull * 1024) +
                      (size_t)row * 1024 + (col & 1023)] = f2bf(v);
                } else {
                    short* o = (short*)out;
                    o[(size_t)row * N + col] = f2bf(v);
                }
            }
        }
    }
}

// ---------------- flash attention (causal): swapped QK^T, 3-ring, vmcnt --------
// R16-proven version. grid (16, H, B); 512 threads; wave w owns 16 q-rows;
// KV tiles of 64. S^T = mfma(K, Q). Causal balance: qblk mixed over (xx, b).
// exp2 softmax, defer-max 11.5. Wave-uniform skip of fully-masked tiles.
__global__ __launch_bounds__(512) void attn_kernel(
    const short* __restrict__ Q, const short* __restrict__ K,
    const short* __restrict__ Vt, short* __restrict__ O)
{
    __shared__ short Kbuf[3][64 * 64];
    __shared__ short Vbuf[3][64 * 64];
    __shared__ short Ps[8][16 * 72];   // per-wave P [16 q][64 kv + pad]

    const int xx = blockIdx.x;          // 0..15
    const int h = blockIdx.y, b = blockIdx.z;
    const int pr = xx >> 1;
    const int u = (pr + b * 2) & 7;
    const int qblk = ((xx + b) & 1) ? (15 - u) : u;   // balanced causal work
    const int tid = threadIdx.x;
    const int w = tid >> 6, l = tid & 63;
    const int lg = l >> 4, li = l & 15;
    const size_t headQ = ((size_t)b * L_) * D_ + (size_t)h * DH_;
    const size_t headV = ((size_t)(b * H_ + h) * DH_) * L_;
    const int q0 = qblk * 128;
    const int qw = q0 + w * 16;
    const float sc2 = 0.125f * 1.44269504f;   // scale * log2(e)

    s16x8 qf[2];
    {
        const short* qr = Q + headQ + (size_t)(qw + li) * D_;
        qf[0] = *(const s16x8*)(qr + lg * 8);
        qf[1] = *(const s16x8*)(qr + 32 + lg * 8);
    }

    const int srow = tid >> 3;
    const int schk = (tid & 7) ^ (srow & 7);
    const short* kSrc = K + headQ + (size_t)srow * D_ + schk * 8;
    const short* vSrc = Vt + headV + (size_t)srow * L_ + schk * 8;

    int koff0[4], koff1[4];
#pragma unroll
    for (int blk = 0; blk < 4; ++blk) {
        const int row = blk * 16 + li;
        const int hh = row & 7;
        koff0[blk] = row * 64 + ((lg ^ hh) * 8);
        koff1[blk] = row * 64 + (((lg + 4) ^ hh) * 8);
    }

    float m_r = -1e30f, l_r = 0.f;
    f32x4 oacc[4] = {};
    short* pw = &Ps[w][0];

    const int nt = 2 * qblk + 2;

    gload_lds16(kSrc, &Kbuf[0][tid * 8]);
    gload_lds16(vSrc, &Vbuf[0][tid * 8]);

    int cur = 0, nxt = 1;
    for (int t = 0; t < nt; ++t) {
        const int kv0 = t * 64;
        if (t + 1 < nt) {
            const int nkv = kv0 + 64;
            gload_lds16(kSrc + (size_t)nkv * D_, &Kbuf[nxt][tid * 8]);
            gload_lds16(vSrc + nkv, &Vbuf[nxt][tid * 8]);
            asm volatile("s_waitcnt vmcnt(2)" ::: "memory");
        } else {
            asm volatile("s_waitcnt vmcnt(0)" ::: "memory");
        }
        __builtin_amdgcn_s_barrier();
        __builtin_amdgcn_sched_barrier(0);

        if (kv0 <= qw + 15) {   // wave-uniform: tile has unmasked work
            const short* kb = &Kbuf[cur][0];
            const short* vb = &Vbuf[cur][0];

            f32x4 s[4];
            __builtin_amdgcn_s_setprio(1);
#pragma unroll
            for (int blk = 0; blk < 4; ++blk) {
                const s16x8 kf0 = *(const s16x8*)&kb[koff0[blk]];
                const s16x8 kf1 = *(const s16x8*)&kb[koff1[blk]];
                f32x4 c = {0.f, 0.f, 0.f, 0.f};
                c = __builtin_amdgcn_mfma_f32_16x16x32_bf16(kf0, qf[0], c, 0, 0, 0);
                c = __builtin_amdgcn_mfma_f32_16x16x32_bf16(kf1, qf[1], c, 0, 0, 0);
                s[blk] = c;
            }
            __builtin_amdgcn_s_setprio(0);

            if (kv0 + 63 > qw) {
                const int q = qw + li;
#pragma unroll
                for (int blk = 0; blk < 4; ++blk) {
                    const int kvb = kv0 + blk * 16 + lg * 4;
#pragma unroll
                    for (int r = 0; r < 4; ++r)
                        if (kvb + r > q) s[blk][r] = -1e30f;
                }
            }

            float mb[4];
#pragma unroll
            for (int blk = 0; blk < 4; ++blk)
                mb[blk] = fmaxf(fmaxf(s[blk][0], s[blk][1]),
                                fmaxf(s[blk][2], s[blk][3]));
            float mm = fmaxf(fmaxf(mb[0], mb[1]), fmaxf(mb[2], mb[3]));
            mm = fmaxf(mm, __shfl_xor(mm, 16));
            mm = fmaxf(mm, __shfl_xor(mm, 32));
            const float mxs = mm * sc2;

            float p[4][4];
            if (__all(mxs <= m_r + 11.5f)) {
                float ps[4];
#pragma unroll
                for (int blk = 0; blk < 4; ++blk) {
#pragma unroll
                    for (int r = 0; r < 4; ++r)
                        p[blk][r] = __builtin_amdgcn_exp2f(
                            fmaf(s[blk][r], sc2, -m_r));
                    ps[blk] = (p[blk][0] + p[blk][1]) + (p[blk][2] + p[blk][3]);
                }
                float sum = (ps[0] + ps[1]) + (ps[2] + ps[3]);
                sum += __shfl_xor(sum, 16);
                sum += __shfl_xor(sum, 32);
                l_r += sum;
            } else {
                const float mn = fmaxf(m_r, mxs);
                const float fac = __builtin_amdgcn_exp2f(m_r - mn);
                m_r = mn;
                float ps[4];
#pragma unroll
                for (int blk = 0; blk < 4; ++blk) {
#pragma unroll
                    for (int r = 0; r < 4; ++r)
                        p[blk][r] = __builtin_amdgcn_exp2f(
                            fmaf(s[blk][r], sc2, -mn));
                    ps[blk] = (p[blk][0] + p[blk][1]) + (p[blk][2] + p[blk][3]);
                }
                float sum = (ps[0] + ps[1]) + (ps[2] + ps[3]);
                sum += __shfl_xor(sum, 16);
                sum += __shfl_xor(sum, 32);
                l_r = l_r * fac + sum;
#pragma unroll
                for (int d = 0; d < 4; ++d)
#pragma unroll
                    for (int r = 0; r < 4; ++r)
                        oacc[d][r] *= fac;
            }

#pragma unroll
            for (int blk = 0; blk < 4; ++blk) {
                s16x4 pk;
#pragma unroll
                for (int r = 0; r < 4; ++r) pk[r] = f2bf(p[blk][r]);
                *(s16x4*)&pw[li * 72 + blk * 16 + lg * 4] = pk;
            }
            asm volatile("s_waitcnt lgkmcnt(0)" ::: "memory");
            __builtin_amdgcn_sched_barrier(0);
            const s16x8 pa0 = *(const s16x8*)&pw[li * 72 + lg * 8];
            const s16x8 pa1 = *(const s16x8*)&pw[li * 72 + 32 + lg * 8];

            __builtin_amdgcn_s_setprio(1);
#pragma unroll
            for (int dblk = 0; dblk < 4; ++dblk) {
                const s16x8 vf0 = *(const s16x8*)&vb[koff0[dblk]];
                const s16x8 vf1 = *(const s16x8*)&vb[koff1[dblk]];
                oacc[dblk] = __builtin_amdgcn_mfma_f32_16x16x32_bf16(vf0, pa0, oacc[dblk], 0, 0, 0);
                oacc[dblk] = __builtin_amdgcn_mfma_f32_16x16x32_bf16(vf1, pa1, oacc[dblk], 0, 0, 0);
            }
            __builtin_amdgcn_s_setprio(0);
        }

        cur = nxt;
        nxt = (nxt == 2) ? 0 : nxt + 1;
    }

    const float inv = 1.f / l_r;
#pragma unroll
    for (int dblk = 0; dblk < 4; ++dblk) {
        s16x4 ov;
#pragma unroll
        for (int r = 0; r < 4; ++r) ov[r] = f2bf(oacc[dblk][r] * inv);
        *(s16x4*)(O + headQ + (size_t)(qw + li) * D_ + dblk * 16 + lg * 4) = ov;
    }
}

// ---------------- launch --------------------------------------------------------
extern "C" void kernel_launch(void* const* d_in, const int* in_sizes, int n_in,
                              void* d_out, int out_size, void* d_ws, size_t ws_size,
                              hipStream_t stream)
{
    const float* X   = (const float*)d_in[0];
    const float* WQ  = (const float*)d_in[1];
    const float* bQ  = (const float*)d_in[2];
    const float* WK  = (const float*)d_in[3];
    const float* bK  = (const float*)d_in[4];
    const float* WV  = (const float*)d_in[5];
    const float* bV  = (const float*)d_in[6];
    const float* WO  = (const float*)d_in[7];
    const float* bO  = (const float*)d_in[8];
    const float* W1  = (const float*)d_in[9];
    const float* b1  = (const float*)d_in[10];
    const float* W2  = (const float*)d_in[11];
    const float* b2  = (const float*)d_in[12];
    const float* g1  = (const float*)d_in[13];
    const float* be1 = (const float*)d_in[14];
    const float* g2  = (const float*)d_in[15];
    const float* be2 = (const float*)d_in[16];
    float* out = (float*)d_out;

    char* ws = (char*)d_ws;
    const size_t MB = 1u << 20;
    short* WQKVt = (short*)(ws + 0 * MB);  // [3072][1024] (WQt|WKt|WVt contiguous)
    short* WOt = (short*)(ws + 6 * MB);
    short* W1t = (short*)(ws + 8 * MB);    // [4096][1024]
    short* W2t = (short*)(ws + 16 * MB);   // [1024][4096]
    short* Xn  = (short*)(ws + 24 * MB);   // [8192][1024] (LN1, reused for LN2)
    short* Qb  = (short*)(ws + 40 * MB);   // [8192][1024]; Kb=+16MB, Vb=+32MB
    short* Vb  = (short*)(ws + 72 * MB);
    short* Vtb = (short*)(ws + 88 * MB);   // [64*64][2048] V^T
    float* bQKV = (float*)(ws + 88 * MB);  // 3072 f32, dead before vtrans writes Vtb
    short* AV  = (short*)(ws + 72 * MB);   // reuses Vb after vtrans
    short* H1  = (short*)(ws + 40 * MB);   // [8192][4096], reuses Q/K/V (dead)

    const dim3 tb(256);

    // fused: WQ/WK/WV/WO transposes in one launch
    transpose4_kernel<<<dim3(32, 32, 4), tb, 0, stream>>>(
        WQ, WK, WV, WO,
        WQKVt, WQKVt + 1024 * 1024, WQKVt + 2 * 1024 * 1024, WOt, 1024, 1024);
    transpose_kernel<<<dim3(128, 32), tb, 0, stream>>>(W1, W1t, 1024, 4096);
    transpose_kernel<<<dim3(32, 128), tb, 0, stream>>>(W2, W2t, 4096, 1024);
    concat3_kernel<<<dim3(12), tb, 0, stream>>>(bQ, bK, bV, bQKV);

    ln_kernel<<<8192, tb, 0, stream>>>(X, g1, be1, Xn);

    // fused QKV GEMM: N=3072, split outputs to Qb/Kb/Vb
    gemm_kernel<3><<<dim3(12, 64), dim3(512), 0, stream>>>(
        Xn, WQKVt, bQKV, nullptr, Qb, 8192, 3072, 1024);

    vtrans_kernel<<<dim3(L_ / 64, B_ * H_), tb, 0, stream>>>(Vb, Vtb);

    attn_kernel<<<dim3(L_ / 128, H_, B_), dim3(512), 0, stream>>>(
        Qb, Qb + 8192ull * 1024, Vtb, AV);

    gemm_kernel<2><<<dim3(4, 64), dim3(512), 0, stream>>>(
        AV, WOt, bO, X, out, 8192, 1024, 1024);

    ln_kernel<<<8192, tb, 0, stream>>>(out, g2, be2, Xn);

    gemm_kernel<1><<<dim3(16, 64), dim3(512), 0, stream>>>(
        Xn, W1t, b1, nullptr, H1, 8192, 4096, 1024);
    gemm_kernel<2><<<dim3(4, 64), dim3(512), 0, stream>>>(
        H1, W2t, b2, out, out, 8192, 1024, 4096);
}